// Round 11
// baseline (169.819 us; speedup 1.0000x reference)
//
#include <hip/hip_runtime.h>
#include <hip/hip_fp16.h>

// Problem constants (from setup_inputs)
#define BB   4
#define NN   5
#define JJ   15
#define HHH  128
#define WHH  240
#define CBX  80
#define CBY  80
#define CBZ  20
#define PP   (CBX*CBY*CBZ)          // 128000
#define HW   (HHH*WHH)              // 30720
#define IMGW 960.0f
#define IMGH 512.0f
#define RECU 16                     // uint32 per record: 15 j-pairs + 1 pad

// ws layout: one 64B record per (b,y,n,x):
//   uint index = (((b*HHH + y)*NN + n)*WHH + x) * RECU + j
//   record[j] = half2( hm[n,b,j,y,x], hm[n,b,j,y,x+1] )   (x+1 clamped to 239)

// ---------------------------------------------------------------------------
// Pass 1: LDS-tiled pack. Block = one (b,y,n): 15 coalesced row reads ->
// LDS [15][241] (dup col 240 = col 239) -> coalesced packed-f16 writes.
// ---------------------------------------------------------------------------
__global__ __launch_bounds__(256) void pack_kernel(
    const float* __restrict__ hm, unsigned int* __restrict__ ws)
{
    __shared__ float rows[JJ][WHH + 1];   // 241 cols, ~14.5 KB
    int bid = blockIdx.x;                 // B*H*N = 4*128*5 = 2560
    int n = bid % NN;
    int y = (bid / NN) % HHH;
    int b = bid / (NN * HHH);

    const float* src = hm + ((size_t)(n * BB + b) * JJ) * HW + y * WHH;
    for (int idx = threadIdx.x; idx < JJ * (WHH + 1); idx += 256) {
        int j = idx / (WHH + 1);
        int x = idx - j * (WHH + 1);
        int xs = min(x, WHH - 1);
        rows[j][x] = src[j * HW + xs];
    }
    __syncthreads();

    unsigned int* dst = ws + (size_t)((b * HHH + y) * NN + n) * WHH * RECU;
    for (int idx = threadIdx.x; idx < WHH * RECU; idx += 256) {
        int x = idx >> 4;
        int u = idx & 15;
        unsigned int val = 0u;
        if (u < JJ) {
            __half2 h = __halves2half2(__float2half_rn(rows[u][x]),
                                       __float2half_rn(rows[u][x + 1]));
            val = *reinterpret_cast<unsigned int*>(&h);
        }
        dst[idx] = val;
    }
}

// ---------------------------------------------------------------------------
// Pass 2: lane-cooperative gather. tid = v*4 + jg: 4 consecutive lanes read
// the 4 uint4 quarters of the SAME 64B record -> one load instruction per
// (view,row) covers 16 records fully coalesced (16 lines/instr vs 64).
// Each thread accumulates 4 joints (j = jg*4+q); projection math is
// recomputed per jg-lane (VALU has headroom).
// ---------------------------------------------------------------------------
__global__ __launch_bounds__(256) void project_kernel(
    const unsigned int* __restrict__ ws,
    const float* __restrict__ Rm,      // [B,N,3,3]
    const float* __restrict__ Tv,      // [B,N,3]
    const float* __restrict__ fv,      // [B,N,2]
    const float* __restrict__ cv,      // [B,N,2]
    const float* __restrict__ trans,   // [B,N,2,3]
    const float* __restrict__ whv,     // [B,N,2]
    const float* __restrict__ gcv,     // [B,3]
    float* __restrict__ out)           // fused [B,J,P] then grids [B,P,3]
{
    int tid = threadIdx.x;             // 256 = 64 voxels * 4 jgroups
    int jg  = tid & 3;                 // record quarter (j = jg*4+q)
    int v   = tid >> 2;                // voxel within block, 0..63
    int tvox = blockIdx.x * 64 + v;    // global voxel id
    int b = tvox / PP;
    int p = tvox - b * PP;
    int ix  = p / (CBY * CBZ);
    int rem = p - ix * (CBY * CBZ);
    int iy  = rem / CBZ;
    int iz  = rem - iy * CBZ;

    const float stx = 8000.0f / (CBX - 1);
    const float sty = 8000.0f / (CBY - 1);
    const float stz = 2000.0f / (CBZ - 1);
    float gx = -4000.0f + (float)ix * stx + gcv[b * 3 + 0];
    float gy = -4000.0f + (float)iy * sty + gcv[b * 3 + 1];
    float gz = -1000.0f + (float)iz * stz + gcv[b * 3 + 2];

    // grids output (second tuple element) — one jg-lane per voxel writes
    if (jg == 0) {
        float* grids_out = out + (size_t)BB * JJ * PP;
        size_t gb = (size_t)(b * PP + p) * 3;
        grids_out[gb + 0] = gx;
        grids_out[gb + 1] = gy;
        grids_out[gb + 2] = gz;
    }

    float cl0[NN], cr0[NN], cl1[NN], cr1[NN];   // folded coeffs per row
    int   r0[NN], r1[NN];                       // record uint index per row
    float bnd[NN];
    float sumb = 0.0f;

    #pragma unroll
    for (int n = 0; n < NN; ++n) {
        int bn = b * NN + n;
        const float* R = Rm + bn * 9;
        float dx = gx - Tv[bn * 3 + 0];
        float dy = gy - Tv[bn * 3 + 1];
        float dz = gz - Tv[bn * 3 + 2];
        float cx = R[0] * dx + R[1] * dy + R[2] * dz;
        float cy = R[3] * dx + R[4] * dy + R[5] * dz;
        float cz = R[6] * dx + R[7] * dy + R[8] * dz;
        float inv = 1.0f / cz;
        float px = cx * inv * fv[bn * 2 + 0] + cv[bn * 2 + 0];
        float py = cy * inv * fv[bn * 2 + 1] + cv[bn * 2 + 1];
        float w = whv[bn * 2 + 0], h = whv[bn * 2 + 1];
        float bound = (px >= 0.0f && py >= 0.0f && px < w && py < h) ? 1.0f : 0.0f;
        float mwh = fmaxf(w, h);
        px = fminf(fmaxf(px, -1.0f), mwh);
        py = fminf(fmaxf(py, -1.0f), mwh);
        const float* tr = trans + bn * 6;
        float tx = tr[0] * px + tr[1] * py + tr[2];
        float ty = tr[3] * px + tr[4] * py + tr[5];
        tx *= (float)WHH / IMGW;   // 0.25
        ty *= (float)HHH / IMGH;   // 0.25
        float sgx = tx / (float)(WHH - 1) * 2.0f - 1.0f;
        float sgy = ty / (float)(HHH - 1) * 2.0f - 1.0f;
        sgx = fminf(fmaxf(sgx, -1.1f), 1.1f);
        sgy = fminf(fmaxf(sgy, -1.1f), 1.1f);
        float xx = (sgx + 1.0f) * 0.5f * (float)(WHH - 1);
        float yy = (sgy + 1.0f) * 0.5f * (float)(HHH - 1);
        float x0f = floorf(xx), y0f = floorf(yy);
        float wx = xx - x0f, wy = yy - y0f;
        int x0 = (int)x0f, y0 = (int)y0f;

        // x coeffs on the record {h[xb], h[xb+1]} (matches reference gather):
        float axl, axr; int xb;
        if (x0 < 0) {                       // tap0 invalid; tap1 = h[0] iff x0==-1
            axl = (x0 == -1) ? wx : 0.0f; axr = 0.0f; xb = 0;
        } else if (x0 >= WHH - 1) {         // tap1 invalid; tap0 = h[239] iff x0==239
            axl = (x0 == WHH - 1) ? (1.0f - wx) : 0.0f; axr = 0.0f; xb = WHH - 1;
        } else {
            axl = 1.0f - wx; axr = wx; xb = x0;
        }

        float vy0 = (y0 >= 0 && y0 <= HHH - 1) ? 1.0f : 0.0f;
        float vy1 = (y0 + 1 >= 0 && y0 + 1 <= HHH - 1) ? 1.0f : 0.0f;
        int yc0 = min(max(y0, 0), HHH - 1);
        int yc1 = min(max(y0 + 1, 0), HHH - 1);
        float ay0 = (1.0f - wy) * vy0 * bound;
        float ay1 = wy * vy1 * bound;

        cl0[n] = axl * ay0;  cr0[n] = axr * ay0;
        cl1[n] = axl * ay1;  cr1[n] = axr * ay1;
        r0[n] = ((((b * HHH + yc0) * NN + n) * WHH) + xb) * RECU + jg * 4;
        r1[n] = ((((b * HHH + yc1) * NN + n) * WHH) + xb) * RECU + jg * 4;
        bnd[n] = bound;
        sumb += bound;
    }

    float acc0 = 0.0f, acc1 = 0.0f, acc2 = 0.0f, acc3 = 0.0f;

    #pragma unroll
    for (int n = 0; n < NN; ++n) {
        if (bnd[n] != 0.0f) {
            uint4 a = *reinterpret_cast<const uint4*>(ws + r0[n]);
            uint4 c = *reinterpret_cast<const uint4*>(ws + r1[n]);
            float c0l = cl0[n], c0r = cr0[n], c1l = cl1[n], c1r = cr1[n];
            float2 f;
            f = __half22float2(*reinterpret_cast<__half2*>(&a.x));
            acc0 += c0l * f.x + c0r * f.y;
            f = __half22float2(*reinterpret_cast<__half2*>(&a.y));
            acc1 += c0l * f.x + c0r * f.y;
            f = __half22float2(*reinterpret_cast<__half2*>(&a.z));
            acc2 += c0l * f.x + c0r * f.y;
            f = __half22float2(*reinterpret_cast<__half2*>(&a.w));
            acc3 += c0l * f.x + c0r * f.y;
            f = __half22float2(*reinterpret_cast<__half2*>(&c.x));
            acc0 += c1l * f.x + c1r * f.y;
            f = __half22float2(*reinterpret_cast<__half2*>(&c.y));
            acc1 += c1l * f.x + c1r * f.y;
            f = __half22float2(*reinterpret_cast<__half2*>(&c.z));
            acc2 += c1l * f.x + c1r * f.y;
            f = __half22float2(*reinterpret_cast<__half2*>(&c.w));
            acc3 += c1l * f.x + c1r * f.y;
        }
    }

    float denom = 1.0f / (sumb + 1e-6f);
    size_t outb = (size_t)b * JJ * PP + p;
    int j0 = jg * 4;
    float vv;
    vv = fminf(fmaxf(acc0 * denom, 0.0f), 1.0f);
    out[outb + (size_t)(j0 + 0) * PP] = vv;
    vv = fminf(fmaxf(acc1 * denom, 0.0f), 1.0f);
    out[outb + (size_t)(j0 + 1) * PP] = vv;
    vv = fminf(fmaxf(acc2 * denom, 0.0f), 1.0f);
    out[outb + (size_t)(j0 + 2) * PP] = vv;
    if (j0 + 3 < JJ) {
        vv = fminf(fmaxf(acc3 * denom, 0.0f), 1.0f);
        out[outb + (size_t)(j0 + 3) * PP] = vv;
    }
}

extern "C" void kernel_launch(void* const* d_in, const int* in_sizes, int n_in,
                              void* d_out, int out_size, void* d_ws, size_t ws_size,
                              hipStream_t stream) {
    const float* hm    = (const float*)d_in[0];
    const float* Rm    = (const float*)d_in[1];
    const float* Tv    = (const float*)d_in[2];
    const float* fv    = (const float*)d_in[3];
    const float* cv    = (const float*)d_in[4];
    const float* trans = (const float*)d_in[5];
    const float* whv   = (const float*)d_in[6];
    const float* gcv   = (const float*)d_in[7];
    float* out = (float*)d_out;
    unsigned int* ws = (unsigned int*)d_ws;   // 4*128*5*240*64B = 39.3 MB

    // Pass 1: pack heatmaps to f16 x-pair records [B,H,N,W,16u]
    pack_kernel<<<BB * HHH * NN, 256, 0, stream>>>(hm, ws);

    // Pass 2: project + gather + fuse (64 voxels x 4 jgroups per block)
    project_kernel<<<BB * PP / 64, 256, 0, stream>>>(ws, Rm, Tv, fv, cv, trans, whv, gcv, out);
}

// Round 14
// 151.815 us; speedup vs baseline: 1.1186x; 1.1186x over previous
//
#include <hip/hip_runtime.h>
#include <hip/hip_fp16.h>

// Problem constants (from setup_inputs)
#define BB   4
#define NN   5
#define JJ   15
#define HHH  128
#define WHH  240
#define CBX  80
#define CBY  80
#define CBZ  20
#define PP   (CBX*CBY*CBZ)          // 128000
#define HW   (HHH*WHH)              // 30720
#define IMGW 960.0f
#define IMGH 512.0f
#define RECU 16                     // uint32 per record: 15 j-pairs + 1 pad

// ws layout: one 64B record per (b,y,n,x):
//   uint index = (((b*HHH + y)*NN + n)*WHH + x) * RECU + j
//   record[j] = half2( hm[n,b,j,y,x], hm[n,b,j,y,x+1] )   (x+1 clamped to 239)

// ---------------------------------------------------------------------------
// Pass 1: LDS-tiled pack. Block = one (b,y,n): 15 coalesced row reads ->
// LDS [15][241] (dup col 240 = col 239) -> coalesced packed-f16 writes.
// ---------------------------------------------------------------------------
__global__ __launch_bounds__(256) void pack_kernel(
    const float* __restrict__ hm, unsigned int* __restrict__ ws)
{
    __shared__ float rows[JJ][WHH + 1];   // 241 cols, ~14.5 KB
    int bid = blockIdx.x;                 // B*H*N = 4*128*5 = 2560
    int n = bid % NN;
    int y = (bid / NN) % HHH;
    int b = bid / (NN * HHH);

    const float* src = hm + ((size_t)(n * BB + b) * JJ) * HW + y * WHH;
    for (int idx = threadIdx.x; idx < JJ * (WHH + 1); idx += 256) {
        int j = idx / (WHH + 1);
        int x = idx - j * (WHH + 1);
        int xs = min(x, WHH - 1);
        rows[j][x] = src[j * HW + xs];
    }
    __syncthreads();

    unsigned int* dst = ws + (size_t)((b * HHH + y) * NN + n) * WHH * RECU;
    for (int idx = threadIdx.x; idx < WHH * RECU; idx += 256) {
        int x = idx >> 4;
        int u = idx & 15;
        unsigned int val = 0u;
        if (u < JJ) {
            __half2 h = __halves2half2(__float2half_rn(rows[u][x]),
                                       __float2half_rn(rows[u][x + 1]));
            val = *reinterpret_cast<unsigned int*>(&h);
        }
        dst[idx] = val;
    }
}

// ---------------------------------------------------------------------------
// Pass 2: quad-cooperative. tid = v*4 + jg. The 4 jg-lanes of voxel v are
// consecutive lanes of one wave:
//   - projection phase: lane jg computes view n=jg; lane 0 also computes
//     view 4 (exec-masked). 7 values/view broadcast via __shfl width=4.
//   - gather phase: the 4 lanes read the 4 uint4 quarters of the SAME 64B
//     record -> 16 lines per load instruction (fully coalesced).
//   - each lane accumulates 4 joints (j = jg*4+q).
// ---------------------------------------------------------------------------
__global__ __launch_bounds__(256) void project_kernel(
    const unsigned int* __restrict__ ws,
    const float* __restrict__ Rm,      // [B,N,3,3]
    const float* __restrict__ Tv,      // [B,N,3]
    const float* __restrict__ fv,      // [B,N,2]
    const float* __restrict__ cv,      // [B,N,2]
    const float* __restrict__ trans,   // [B,N,2,3]
    const float* __restrict__ whv,     // [B,N,2]
    const float* __restrict__ gcv,     // [B,3]
    float* __restrict__ out)           // fused [B,J,P] then grids [B,P,3]
{
    int tid = threadIdx.x;             // 256 = 64 voxels * 4 jgroups
    int jg  = tid & 3;                 // record quarter (j = jg*4+q)
    int v   = tid >> 2;                // voxel within block, 0..63
    int tvox = blockIdx.x * 64 + v;    // global voxel id
    int b = tvox / PP;
    int p = tvox - b * PP;
    int ix  = p / (CBY * CBZ);
    int rem = p - ix * (CBY * CBZ);
    int iy  = rem / CBZ;
    int iz  = rem - iy * CBZ;

    const float stx = 8000.0f / (CBX - 1);
    const float sty = 8000.0f / (CBY - 1);
    const float stz = 2000.0f / (CBZ - 1);
    float gx = -4000.0f + (float)ix * stx + gcv[b * 3 + 0];
    float gy = -4000.0f + (float)iy * sty + gcv[b * 3 + 1];
    float gz = -1000.0f + (float)iz * stz + gcv[b * 3 + 2];

    // grids output (second tuple element) — one jg-lane per voxel writes
    if (jg == 0) {
        float* grids_out = out + (size_t)BB * JJ * PP;
        size_t gb = (size_t)(b * PP + p) * 3;
        grids_out[gb + 0] = gx;
        grids_out[gb + 1] = gy;
        grids_out[gb + 2] = gz;
    }

    // --- projection phase: slot 0 = view jg (all lanes), slot 1 = view 4
    // (lane jg==0 only, exec-masked). Static 2-slot arrays, unrolled.
    float m_cl0[2] = {0.f, 0.f}, m_cr0[2] = {0.f, 0.f};
    float m_cl1[2] = {0.f, 0.f}, m_cr1[2] = {0.f, 0.f};
    float m_bnd[2] = {0.f, 0.f};
    int   m_r0[2]  = {0, 0},     m_r1[2]  = {0, 0};

    #pragma unroll
    for (int s = 0; s < 2; ++s) {
        int n = (s == 0) ? jg : 4;
        bool active = (s == 0) || (jg == 0);
        if (active) {
            int bn = b * NN + n;
            const float* R = Rm + bn * 9;
            float dx = gx - Tv[bn * 3 + 0];
            float dy = gy - Tv[bn * 3 + 1];
            float dz = gz - Tv[bn * 3 + 2];
            float cx = R[0] * dx + R[1] * dy + R[2] * dz;
            float cy = R[3] * dx + R[4] * dy + R[5] * dz;
            float cz = R[6] * dx + R[7] * dy + R[8] * dz;
            float inv = 1.0f / cz;
            float px = cx * inv * fv[bn * 2 + 0] + cv[bn * 2 + 0];
            float py = cy * inv * fv[bn * 2 + 1] + cv[bn * 2 + 1];
            float w = whv[bn * 2 + 0], h = whv[bn * 2 + 1];
            float bound = (px >= 0.0f && py >= 0.0f && px < w && py < h) ? 1.0f : 0.0f;
            float mwh = fmaxf(w, h);
            px = fminf(fmaxf(px, -1.0f), mwh);
            py = fminf(fmaxf(py, -1.0f), mwh);
            const float* tr = trans + bn * 6;
            float tx = tr[0] * px + tr[1] * py + tr[2];
            float ty = tr[3] * px + tr[4] * py + tr[5];
            tx *= (float)WHH / IMGW;   // 0.25
            ty *= (float)HHH / IMGH;   // 0.25
            float sgx = tx / (float)(WHH - 1) * 2.0f - 1.0f;
            float sgy = ty / (float)(HHH - 1) * 2.0f - 1.0f;
            sgx = fminf(fmaxf(sgx, -1.1f), 1.1f);
            sgy = fminf(fmaxf(sgy, -1.1f), 1.1f);
            float xx = (sgx + 1.0f) * 0.5f * (float)(WHH - 1);
            float yy = (sgy + 1.0f) * 0.5f * (float)(HHH - 1);
            float x0f = floorf(xx), y0f = floorf(yy);
            float wx = xx - x0f, wy = yy - y0f;
            int x0 = (int)x0f, y0 = (int)y0f;

            float axl, axr; int xb;
            if (x0 < 0) {                       // tap1 = h[0] iff x0==-1
                axl = (x0 == -1) ? wx : 0.0f; axr = 0.0f; xb = 0;
            } else if (x0 >= WHH - 1) {         // tap0 = h[239] iff x0==239
                axl = (x0 == WHH - 1) ? (1.0f - wx) : 0.0f; axr = 0.0f; xb = WHH - 1;
            } else {
                axl = 1.0f - wx; axr = wx; xb = x0;
            }

            float vy0 = (y0 >= 0 && y0 <= HHH - 1) ? 1.0f : 0.0f;
            float vy1 = (y0 + 1 >= 0 && y0 + 1 <= HHH - 1) ? 1.0f : 0.0f;
            int yc0 = min(max(y0, 0), HHH - 1);
            int yc1 = min(max(y0 + 1, 0), HHH - 1);
            float ay0 = (1.0f - wy) * vy0 * bound;
            float ay1 = wy * vy1 * bound;

            m_cl0[s] = axl * ay0;  m_cr0[s] = axr * ay0;
            m_cl1[s] = axl * ay1;  m_cr1[s] = axr * ay1;
            m_r0[s] = (((b * HHH + yc0) * NN + n) * WHH + xb) * RECU;
            m_r1[s] = (((b * HHH + yc1) * NN + n) * WHH + xb) * RECU;
            m_bnd[s] = bound;
        }
    }

    // --- quad-broadcast all 5 views' parameters (width=4 shfl)
    float acc0 = 0.0f, acc1 = 0.0f, acc2 = 0.0f, acc3 = 0.0f;
    float sumb = 0.0f;

    #pragma unroll
    for (int n = 0; n < NN; ++n) {
        const int sj = (n < 4) ? n : 0;
        float scl0 = (n < 4) ? m_cl0[0] : m_cl0[1];
        float scr0 = (n < 4) ? m_cr0[0] : m_cr0[1];
        float scl1 = (n < 4) ? m_cl1[0] : m_cl1[1];
        float scr1 = (n < 4) ? m_cr1[0] : m_cr1[1];
        float sbn  = (n < 4) ? m_bnd[0] : m_bnd[1];
        int   sr0  = (n < 4) ? m_r0[0]  : m_r0[1];
        int   sr1  = (n < 4) ? m_r1[0]  : m_r1[1];

        float c0l = __shfl(scl0, sj, 4);
        float c0r = __shfl(scr0, sj, 4);
        float c1l = __shfl(scl1, sj, 4);
        float c1r = __shfl(scr1, sj, 4);
        float bb  = __shfl(sbn,  sj, 4);
        int   r0  = __shfl(sr0,  sj, 4) + jg * 4;
        int   r1  = __shfl(sr1,  sj, 4) + jg * 4;
        sumb += bb;

        if (bb != 0.0f) {
            uint4 a = *reinterpret_cast<const uint4*>(ws + r0);
            uint4 c = *reinterpret_cast<const uint4*>(ws + r1);
            float2 f;
            f = __half22float2(*reinterpret_cast<__half2*>(&a.x));
            acc0 += c0l * f.x + c0r * f.y;
            f = __half22float2(*reinterpret_cast<__half2*>(&a.y));
            acc1 += c0l * f.x + c0r * f.y;
            f = __half22float2(*reinterpret_cast<__half2*>(&a.z));
            acc2 += c0l * f.x + c0r * f.y;
            f = __half22float2(*reinterpret_cast<__half2*>(&a.w));
            acc3 += c0l * f.x + c0r * f.y;
            f = __half22float2(*reinterpret_cast<__half2*>(&c.x));
            acc0 += c1l * f.x + c1r * f.y;
            f = __half22float2(*reinterpret_cast<__half2*>(&c.y));
            acc1 += c1l * f.x + c1r * f.y;
            f = __half22float2(*reinterpret_cast<__half2*>(&c.z));
            acc2 += c1l * f.x + c1r * f.y;
            f = __half22float2(*reinterpret_cast<__half2*>(&c.w));
            acc3 += c1l * f.x + c1r * f.y;
        }
    }

    float denom = 1.0f / (sumb + 1e-6f);
    size_t outb = (size_t)b * JJ * PP + p;
    int j0 = jg * 4;
    float vv;
    vv = fminf(fmaxf(acc0 * denom, 0.0f), 1.0f);
    out[outb + (size_t)(j0 + 0) * PP] = vv;
    vv = fminf(fmaxf(acc1 * denom, 0.0f), 1.0f);
    out[outb + (size_t)(j0 + 1) * PP] = vv;
    vv = fminf(fmaxf(acc2 * denom, 0.0f), 1.0f);
    out[outb + (size_t)(j0 + 2) * PP] = vv;
    if (j0 + 3 < JJ) {
        vv = fminf(fmaxf(acc3 * denom, 0.0f), 1.0f);
        out[outb + (size_t)(j0 + 3) * PP] = vv;
    }
}

extern "C" void kernel_launch(void* const* d_in, const int* in_sizes, int n_in,
                              void* d_out, int out_size, void* d_ws, size_t ws_size,
                              hipStream_t stream) {
    const float* hm    = (const float*)d_in[0];
    const float* Rm    = (const float*)d_in[1];
    const float* Tv    = (const float*)d_in[2];
    const float* fv    = (const float*)d_in[3];
    const float* cv    = (const float*)d_in[4];
    const float* trans = (const float*)d_in[5];
    const float* whv   = (const float*)d_in[6];
    const float* gcv   = (const float*)d_in[7];
    float* out = (float*)d_out;
    unsigned int* ws = (unsigned int*)d_ws;   // 4*128*5*240*64B = 39.3 MB

    // Pass 1: pack heatmaps to f16 x-pair records [B,H,N,W,16u]
    pack_kernel<<<BB * HHH * NN, 256, 0, stream>>>(hm, ws);

    // Pass 2: project + gather + fuse (64 voxels x 4 jgroups per block)
    project_kernel<<<BB * PP / 64, 256, 0, stream>>>(ws, Rm, Tv, fv, cv, trans, whv, gcv, out);
}